// Round 1
// baseline (755.624 us; speedup 1.0000x reference)
//
#include <hip/hip_runtime.h>

// GRU: H=32, I=1, B=2048, T=1024, fused output Linear(32,1).
// Mapping: half-wave (32 lanes) per batch element; lane j owns h[j] and the
// three W_hh rows {j, 32+j, 64+j} in registers (96 VGPRs). Per step:
//   1 ds_write_b32 (publish h) + 8 ds_read_b128 (broadcast all 32 h)
//   96 v_fma (the FLOP floor) + gates + shfl_xor y-reduction.
// 2 batches/wave -> 1024 waves ~= 1 wave/SIMD on 256 CUs.

constexpr int H  = 32;
constexpr int TT = 1024;
constexpr int BB = 2048;

__device__ __forceinline__ float fast_rcp(float a) {
    return __builtin_amdgcn_rcpf(a);
}

__global__ void gru_fused(const float* __restrict__ x,      // [B,T]
                          const float* __restrict__ h0,     // [1,B,H]
                          const float* __restrict__ W_ih,   // [3H,1]
                          const float* __restrict__ W_hh,   // [3H,H]
                          const float* __restrict__ b_ih,   // [3H]
                          const float* __restrict__ b_hh,   // [3H]
                          const float* __restrict__ W_out,  // [1,H]
                          const float* __restrict__ b_out,  // [1]
                          float* __restrict__ out)          // y[B,T] ++ h_n[B,H]
{
    __shared__ __align__(16) float hbuf[8][H];   // [batch-slot][unit], 1 KB

    const int tid   = threadIdx.x;
    const int warp  = tid >> 6;
    const int lane  = tid & 63;
    const int half  = lane >> 5;
    const int j     = lane & 31;          // hidden unit owned by this lane
    const int bslot = (warp << 1) | half; // 0..7 within block
    const int b     = (blockIdx.x << 3) | bslot;

    // --- one-time parameter loads (registers) ---
    float Wr[H], Wz[H], Wn[H];
#pragma unroll
    for (int k = 0; k < H; ++k) {
        Wr[k] = W_hh[(0 * H + j) * H + k];
        Wz[k] = W_hh[(1 * H + j) * H + k];
        Wn[k] = W_hh[(2 * H + j) * H + k];
    }
    const float wir = W_ih[j];
    const float wiz = W_ih[H + j];
    const float win = W_ih[2 * H + j];
    const float br  = b_ih[j]     + b_hh[j];        // r-gate bias (merged)
    const float bz  = b_ih[H + j] + b_hh[H + j];    // z-gate bias (merged)
    const float bin = b_ih[2 * H + j];              // n-gate input bias
    const float bhn = b_hh[2 * H + j];              // n-gate hidden bias (inside r*)
    const float wo  = W_out[j];
    const float bo  = b_out[0];

    float h = h0[b * H + j];

    const float* xb = x + (size_t)b * TT;
    float*       yb = out + (size_t)b * TT;

    for (int t0 = 0; t0 < TT; t0 += 32) {
        const float xv = xb[t0 + j];   // coalesced chunk of 32 timesteps
        float ystash = 0.0f;

        for (int s = 0; s < 32; ++s) {
            // publish h and re-read all 32 units (broadcast reads, conflict-free)
            hbuf[bslot][j] = h;
            __builtin_amdgcn_wave_barrier();
            const float4* hp = (const float4*)(&hbuf[bslot][0]);
            float4 hq[8];
#pragma unroll
            for (int i = 0; i < 8; ++i) hq[i] = hp[i];

            const float xt = __shfl(xv, s, 32);

            float accr = __builtin_fmaf(xt, wir, br);
            float accz = __builtin_fmaf(xt, wiz, bz);
            float accn = bhn;
#pragma unroll
            for (int i = 0; i < 8; ++i) {
                accr = __builtin_fmaf(Wr[4 * i + 0], hq[i].x, accr);
                accz = __builtin_fmaf(Wz[4 * i + 0], hq[i].x, accz);
                accn = __builtin_fmaf(Wn[4 * i + 0], hq[i].x, accn);
                accr = __builtin_fmaf(Wr[4 * i + 1], hq[i].y, accr);
                accz = __builtin_fmaf(Wz[4 * i + 1], hq[i].y, accz);
                accn = __builtin_fmaf(Wn[4 * i + 1], hq[i].y, accn);
                accr = __builtin_fmaf(Wr[4 * i + 2], hq[i].z, accr);
                accz = __builtin_fmaf(Wz[4 * i + 2], hq[i].z, accz);
                accn = __builtin_fmaf(Wn[4 * i + 2], hq[i].z, accn);
                accr = __builtin_fmaf(Wr[4 * i + 3], hq[i].w, accr);
                accz = __builtin_fmaf(Wz[4 * i + 3], hq[i].w, accz);
                accn = __builtin_fmaf(Wn[4 * i + 3], hq[i].w, accn);
            }

            // gates (saturation-safe forms: no inf-inf)
            const float r = fast_rcp(1.0f + __expf(-accr));
            const float z = fast_rcp(1.0f + __expf(-accz));
            const float xpn  = __builtin_fmaf(xt, win, bin);
            const float npre = __builtin_fmaf(r, accn, xpn);
            const float n = 1.0f - 2.0f * fast_rcp(1.0f + __expf(2.0f * npre));

            h = __builtin_fmaf(z, h - n, n);   // (1-z)*n + z*h

            // y_t = W_out . h + b_out  (butterfly reduce within half-wave)
            float yv = wo * h;
#pragma unroll
            for (int m = 16; m; m >>= 1) yv += __shfl_xor(yv, m);
            ystash = (j == s) ? (yv + bo) : ystash;
        }

        yb[t0 + j] = ystash;   // coalesced 128B store per half-wave
    }

    out[(size_t)BB * TT + b * H + j] = h;   // h_n
}

extern "C" void kernel_launch(void* const* d_in, const int* in_sizes, int n_in,
                              void* d_out, int out_size, void* d_ws, size_t ws_size,
                              hipStream_t stream) {
    const float* x     = (const float*)d_in[0];
    const float* h0    = (const float*)d_in[1];
    const float* W_ih  = (const float*)d_in[2];
    const float* W_hh  = (const float*)d_in[3];
    const float* b_ih  = (const float*)d_in[4];
    const float* b_hh  = (const float*)d_in[5];
    const float* W_out = (const float*)d_in[6];
    const float* b_out = (const float*)d_in[7];
    float* out = (float*)d_out;

    dim3 grid(BB / 8);   // 256 blocks, 8 batches each
    dim3 block(256);     // 4 waves
    gru_fused<<<grid, block, 0, stream>>>(x, h0, W_ih, W_hh, b_ih, b_hh,
                                          W_out, b_out, out);
}

// Round 2
// 399.051 us; speedup vs baseline: 1.8936x; 1.8936x over previous
//
#include <hip/hip_runtime.h>

// GRU: H=32, I=1, B=2048, T=1024, fused output Linear(32,1).
//
// Mapping v2: ONE full 64-lane wave per batch element. Lane (half, j) owns
// hidden row j of all 3 gates and accumulates the k-range [16*half, 16*half+16)
// (48 weight VGPRs). Partial gate sums combine with one shfl_xor(.,32) each.
// -> 2048 waves = 2 waves/SIMD (vs 1 in v1) for latency hiding, and
// __launch_bounds__(256,2) lifts the 64-VGPR cap that forced v1 to reload
// weights from memory every step.
//
// Per step per wave: 1 ds_write_b32 (publish h, both halves -> 2 copies),
// 4 ds_read_b128 broadcast (own k-half), 48 v_fma (the FLOP floor),
// 3 shfl_xor combines, gates, 1 ds_write_b32 into a y-transpose buffer.
// y reduction is amortized: every 32 steps, 32 conflict-free ds_read_b32 + adds.

constexpr int H  = 32;
constexpr int TT = 1024;
constexpr int BB = 2048;

__device__ __forceinline__ float fast_rcp(float a) {
    return __builtin_amdgcn_rcpf(a);
}

__global__ __launch_bounds__(256, 2)
void gru_fused(const float* __restrict__ x,      // [B,T]
               const float* __restrict__ h0,     // [1,B,H]
               const float* __restrict__ W_ih,   // [3H,1]
               const float* __restrict__ W_hh,   // [3H,H]
               const float* __restrict__ b_ih,   // [3H]
               const float* __restrict__ b_hh,   // [3H]
               const float* __restrict__ W_out,  // [1,H]
               const float* __restrict__ b_out,  // [1]
               float* __restrict__ out)          // y[B,T] ++ h_n[B,H]
{
    __shared__ __align__(16) float hbuf[4][64];       // [wave][2 copies of h]
    __shared__ float ybuf[4][33 * 33];                // rows 0..31: y transpose; tail: junk dump

    const int tid  = threadIdx.x;
    const int w    = tid >> 6;          // wave in block = batch slot
    const int lane = tid & 63;
    const int half = lane >> 5;         // k-range selector
    const int j    = lane & 31;         // hidden unit (gate row) owned
    const int b    = (blockIdx.x << 2) | w;

    // --- weights: rows {j, H+j, 2H+j} of W_hh, own k-half only (48 VGPRs) ---
    float Wr[16], Wz[16], Wn[16];
    const int kbase = 16 * half;
#pragma unroll
    for (int k = 0; k < 16; ++k) {
        Wr[k] = W_hh[(0 * H + j) * H + kbase + k];
        Wz[k] = W_hh[(1 * H + j) * H + kbase + k];
        Wn[k] = W_hh[(2 * H + j) * H + kbase + k];
    }
    // bias / input-weight terms enter the accumulators exactly once: zero them
    // on half 1 (partial sums are added across halves).
    const float wir = half ? 0.0f : W_ih[j];
    const float wiz = half ? 0.0f : W_ih[H + j];
    const float br  = half ? 0.0f : (b_ih[j] + b_hh[j]);
    const float bz  = half ? 0.0f : (b_ih[H + j] + b_hh[H + j]);
    const float bhn = half ? 0.0f : b_hh[2 * H + j];
    // used after the combine (full lanes): keep on both halves
    const float win = W_ih[2 * H + j];
    const float bin = b_ih[2 * H + j];
    const float wo  = W_out[j];
    const float bo  = b_out[0];

    float h = h0[b * H + j];

    const float* xb = x + (size_t)b * TT;
    float*       yb = out + (size_t)b * TT;

    // y-transpose write address: half0 -> row s, col j; half1 -> junk row (distinct
    // addresses, 2-way bank aliasing with half0 = free). Branchless per step.
    const int ybase = half ? (32 * 33 + j) : j;
    const int ystep = half ? 0 : 33;
    float* yrow = &ybuf[w][0];

    const float4* hp = (const float4*)&hbuf[w][48 * half];  // half0: words 0..15, half1: 48..63

    for (int t0 = 0; t0 < TT; t0 += 32) {
        const float xv = xb[t0 + j];   // lane j holds x[t0+j] (both halves)

        for (int s = 0; s < 32; ++s) {
            // publish h (both halves write duplicate copies), read back own k-half
            hbuf[w][lane] = h;
            __builtin_amdgcn_wave_barrier();
            float4 q0 = hp[0], q1 = hp[1], q2 = hp[2], q3 = hp[3];

            const float xt = __uint_as_float(
                __builtin_amdgcn_readlane(__float_as_uint(xv), s));

            float accr = __builtin_fmaf(xt, wir, br);
            float accz = __builtin_fmaf(xt, wiz, bz);
            float accn = bhn;
#pragma unroll
            for (int i = 0; i < 4; ++i) {
                const float4 q = (i == 0) ? q0 : (i == 1) ? q1 : (i == 2) ? q2 : q3;
                accr = __builtin_fmaf(Wr[4 * i + 0], q.x, accr);
                accz = __builtin_fmaf(Wz[4 * i + 0], q.x, accz);
                accn = __builtin_fmaf(Wn[4 * i + 0], q.x, accn);
                accr = __builtin_fmaf(Wr[4 * i + 1], q.y, accr);
                accz = __builtin_fmaf(Wz[4 * i + 1], q.y, accz);
                accn = __builtin_fmaf(Wn[4 * i + 1], q.y, accn);
                accr = __builtin_fmaf(Wr[4 * i + 2], q.z, accr);
                accz = __builtin_fmaf(Wz[4 * i + 2], q.z, accz);
                accn = __builtin_fmaf(Wn[4 * i + 2], q.z, accn);
                accr = __builtin_fmaf(Wr[4 * i + 3], q.w, accr);
                accz = __builtin_fmaf(Wz[4 * i + 3], q.w, accz);
                accn = __builtin_fmaf(Wn[4 * i + 3], q.w, accn);
            }
            // combine the two k-halves
            accr += __shfl_xor(accr, 32);
            accz += __shfl_xor(accz, 32);
            accn += __shfl_xor(accn, 32);

            // gates (saturation-safe, no inf-inf)
            const float r = fast_rcp(1.0f + __expf(-accr));
            const float z = fast_rcp(1.0f + __expf(-accz));
            const float xpn  = __builtin_fmaf(xt, win, bin);
            const float npre = __builtin_fmaf(r, accn, xpn);
            const float n = 1.0f - 2.0f * fast_rcp(1.0f + __expf(2.0f * npre));

            h = __builtin_fmaf(z, h - n, n);   // (1-z)*n + z*h

            // stash y contribution into transpose buffer (1 conflict-free write)
            yrow[ybase + ystep * s] = wo * h;
        }

        // amortized y reduction: lane (half, j) sums row j (32 entries written by
        // half0 lanes). Banks (j+k)&31 -> conflict-free; halves read same addr
        // (broadcast). Then half0 stores 32 consecutive timesteps (coalesced).
        __builtin_amdgcn_wave_barrier();
        float s0 = 0.0f, s1 = 0.0f, s2 = 0.0f, s3 = 0.0f;
#pragma unroll
        for (int k = 0; k < 32; k += 4) {
            s0 += yrow[33 * j + k + 0];
            s1 += yrow[33 * j + k + 1];
            s2 += yrow[33 * j + k + 2];
            s3 += yrow[33 * j + k + 3];
        }
        if (half == 0) {
            yb[t0 + j] = (s0 + s1) + (s2 + s3) + bo;
        }
        __builtin_amdgcn_wave_barrier();   // don't let next chunk's writes pass the reads
    }

    if (half == 0) {
        out[(size_t)BB * TT + b * H + j] = h;   // h_n
    }
}

extern "C" void kernel_launch(void* const* d_in, const int* in_sizes, int n_in,
                              void* d_out, int out_size, void* d_ws, size_t ws_size,
                              hipStream_t stream) {
    const float* x     = (const float*)d_in[0];
    const float* h0    = (const float*)d_in[1];
    const float* W_ih  = (const float*)d_in[2];
    const float* W_hh  = (const float*)d_in[3];
    const float* b_ih  = (const float*)d_in[4];
    const float* b_hh  = (const float*)d_in[5];
    const float* W_out = (const float*)d_in[6];
    const float* b_out = (const float*)d_in[7];
    float* out = (float*)d_out;

    dim3 grid(BB / 4);   // 512 blocks, 4 batches (waves) each
    dim3 block(256);     // 4 waves
    gru_fused<<<grid, block, 0, stream>>>(x, h0, W_ih, W_hh, b_ih, b_hh,
                                          W_out, b_out, out);
}

// Round 3
// 369.949 us; speedup vs baseline: 2.0425x; 1.0787x over previous
//
#include <hip/hip_runtime.h>

// GRU: H=32, I=1, B=2048, T=1024, fused output Linear(32,1).
// Mapping: 1 batch per 64-lane wave (2048 waves = 2/SIMD). Lane (half, j)
// owns gate rows {r,z,n} of unit j for K-range [16*half, 16*half+16).
// v3: codegen-focused rewrite of v2 —
//  * 12 named float4 weight regs + 4 named float4 h-frag regs (force residency)
//  * inner 32-step loop fully unrolled: readlane lanes and all LDS offsets
//    become immediates; y-store is base + 33*s (constant offset), half1 lands
//    in a junk region sized so no wrap occurs
//  * raw ds_bpermute (hoisted addr) for the 3 K-half combines
//  * exp2-based sigmoid/tanh (4 transcendentals/step, saturation-safe)

constexpr int H  = 32;
constexpr int TT = 1024;
constexpr int BB = 2048;

__device__ __forceinline__ float rcp_(float a)  { return __builtin_amdgcn_rcpf(a); }
__device__ __forceinline__ float exp2_(float a) { return __builtin_amdgcn_exp2f(a); }
__device__ __forceinline__ float bperm_(int bp, float v) {
    return __uint_as_float((unsigned)__builtin_amdgcn_ds_bpermute(bp, (int)__float_as_uint(v)));
}

__global__ __launch_bounds__(256, 2)
void gru_fused(const float* __restrict__ x,      // [B,T]
               const float* __restrict__ h0,     // [1,B,H]
               const float* __restrict__ W_ih,   // [3H,1]
               const float* __restrict__ W_hh,   // [3H,H]
               const float* __restrict__ b_ih,   // [3H]
               const float* __restrict__ b_hh,   // [3H]
               const float* __restrict__ W_out,  // [1,H]
               const float* __restrict__ b_out,  // [1]
               float* __restrict__ out)          // y[B,T] ++ h_n[B,H]
{
    __shared__ __align__(16) float hbuf[4][64];    // [wave][2 copies of h]
    __shared__ float ybuf[4][33 * 64];             // rows 0..31 real, 32..63 junk (half1)

    const int tid  = threadIdx.x;
    const int w    = tid >> 6;
    const int lane = tid & 63;
    const int half = lane >> 5;
    const int j    = lane & 31;
    const int b    = (blockIdx.x << 2) | w;

    // --- weights: own K-half of rows {j, H+j, 2H+j}, as 12 named float4 ---
    const float4* Wr4 = (const float4*)&W_hh[(0 * H + j) * H + 16 * half];
    const float4* Wz4 = (const float4*)&W_hh[(1 * H + j) * H + 16 * half];
    const float4* Wn4 = (const float4*)&W_hh[(2 * H + j) * H + 16 * half];
    const float4 wr0 = Wr4[0], wr1 = Wr4[1], wr2 = Wr4[2], wr3 = Wr4[3];
    const float4 wz0 = Wz4[0], wz1 = Wz4[1], wz2 = Wz4[2], wz3 = Wz4[3];
    const float4 wn0 = Wn4[0], wn1 = Wn4[1], wn2 = Wn4[2], wn3 = Wn4[3];

    // bias / input-weight terms enter accumulators once (zero on half1)
    const float wir = half ? 0.0f : W_ih[j];
    const float wiz = half ? 0.0f : W_ih[H + j];
    const float br  = half ? 0.0f : (b_ih[j] + b_hh[j]);
    const float bz  = half ? 0.0f : (b_ih[H + j] + b_hh[H + j]);
    const float bhn = half ? 0.0f : b_hh[2 * H + j];
    const float win = W_ih[2 * H + j];
    const float bin = b_ih[2 * H + j];
    const float wo  = W_out[j];
    const float bo  = b_out[0];

    float h = h0[b * H + j];

    const float* xb = x + (size_t)b * TT;
    float*       yb = out + (size_t)b * TT;

    float* hw = &hbuf[w][0];
    // half0 reads words 0..15 (half0's copy), half1 words 48..63 (half1's copy)
    // -> the two address groups hit disjoint banks.
    const float4* hp = (const float4*)&hbuf[w][48 * half];
    // y transpose: half0 -> rows 0..31 (real), half1 -> rows 32..63 (junk).
    float* yw = &ybuf[w][half * 33 * 32 + j];
    float* yrow = &ybuf[w][0];

    const int bp = (lane ^ 32) << 2;   // ds_bpermute byte address, hoisted

#define FMA3(W_, Q_, C_)                                        \
    accr = __builtin_fmaf(wr##W_.C_, q##Q_.C_, accr);           \
    accz = __builtin_fmaf(wz##W_.C_, q##Q_.C_, accz);           \
    accn = __builtin_fmaf(wn##W_.C_, q##Q_.C_, accn);

#pragma unroll 1
    for (int t0 = 0; t0 < TT; t0 += 32) {
        const float xv = xb[t0 + j];   // lane j holds x[t0+j] (both halves)

#pragma unroll
        for (int s = 0; s < 32; ++s) {
            hw[lane] = h;
            __builtin_amdgcn_wave_barrier();
            const float4 q0 = hp[0], q1 = hp[1], q2 = hp[2], q3 = hp[3];

            const float xt = __uint_as_float(
                (unsigned)__builtin_amdgcn_readlane((int)__float_as_uint(xv), s));

            float accr = __builtin_fmaf(xt, wir, br);
            float accz = __builtin_fmaf(xt, wiz, bz);
            float accn = bhn;
            FMA3(0, 0, x) FMA3(0, 0, y) FMA3(0, 0, z) FMA3(0, 0, w)
            FMA3(1, 1, x) FMA3(1, 1, y) FMA3(1, 1, z) FMA3(1, 1, w)
            FMA3(2, 2, x) FMA3(2, 2, y) FMA3(2, 2, z) FMA3(2, 2, w)
            FMA3(3, 3, x) FMA3(3, 3, y) FMA3(3, 3, z) FMA3(3, 3, w)

            // combine the two K-halves (xor-32 swap + add)
            accr += bperm_(bp, accr);
            accz += bperm_(bp, accz);
            accn += bperm_(bp, accn);

            // gates: sigmoid/tanh via exp2 (saturation-safe)
            const float r = rcp_(1.0f + exp2_(accr * -1.44269504f));
            const float z = rcp_(1.0f + exp2_(accz * -1.44269504f));
            const float xpn  = __builtin_fmaf(xt, win, bin);
            const float npre = __builtin_fmaf(r, accn, xpn);
            const float n = __builtin_fmaf(-2.0f, rcp_(1.0f + exp2_(npre * 2.88539008f)), 1.0f);

            h = __builtin_fmaf(z, h - n, n);   // (1-z)*n + z*h

            yw[33 * s] = wo * h;               // constant-offset ds_write
        }

        // amortized y reduction: lane (half,j) sums row j; halves broadcast-read
        // the same addresses; 33-stride is bank-conflict-free across j.
        __builtin_amdgcn_wave_barrier();
        float s0 = 0.0f, s1 = 0.0f, s2 = 0.0f, s3 = 0.0f;
#pragma unroll
        for (int k = 0; k < 32; k += 4) {
            s0 += yrow[33 * j + k + 0];
            s1 += yrow[33 * j + k + 1];
            s2 += yrow[33 * j + k + 2];
            s3 += yrow[33 * j + k + 3];
        }
        if (half == 0) {
            yb[t0 + j] = (s0 + s1) + (s2 + s3) + bo;
        }
        __builtin_amdgcn_wave_barrier();   // next chunk's writes must not pass reads
    }

    if (half == 0) {
        out[(size_t)BB * TT + b * H + j] = h;   // h_n
    }
#undef FMA3
}

extern "C" void kernel_launch(void* const* d_in, const int* in_sizes, int n_in,
                              void* d_out, int out_size, void* d_ws, size_t ws_size,
                              hipStream_t stream) {
    const float* x     = (const float*)d_in[0];
    const float* h0    = (const float*)d_in[1];
    const float* W_ih  = (const float*)d_in[2];
    const float* W_hh  = (const float*)d_in[3];
    const float* b_ih  = (const float*)d_in[4];
    const float* b_hh  = (const float*)d_in[5];
    const float* W_out = (const float*)d_in[6];
    const float* b_out = (const float*)d_in[7];
    float* out = (float*)d_out;

    dim3 grid(BB / 4);   // 512 blocks, 4 waves (batches) each
    dim3 block(256);
    gru_fused<<<grid, block, 0, stream>>>(x, h0, W_ih, W_hh, b_ih, b_hh,
                                          W_out, b_out, out);
}